// Round 1
// baseline (203.364 us; speedup 1.0000x reference)
//
#include <hip/hip_runtime.h>
#include <hip/hip_bf16.h>
#include <stdint.h>

// Problem constants (from reference)
#define N1 8
#define N2 8
#define PP 1024
#define DD 768
#define PH 32
#define PW 32
#define OH 512
#define OW 512

typedef short bf16x8 __attribute__((ext_vector_type(8)));
typedef float f32x4 __attribute__((ext_vector_type(4)));

// Monotone float<->uint mapping so atomicMax on unsigned == max on float.
__device__ __forceinline__ unsigned f2u_mono(float f) {
  unsigned u = __float_as_uint(f);
  return (u & 0x80000000u) ? ~u : (u | 0x80000000u);
}
__device__ __forceinline__ float u2f_mono(unsigned u) {
  return (u & 0x80000000u) ? __uint_as_float(u & 0x7fffffffu)
                           : __uint_as_float(~u);
}

// ---------------- K1: row L2-normalize f32 -> bf16 ----------------
// One block (256 threads) per row of 768.
__global__ __launch_bounds__(256) void nrm_kernel(
    const float* __restrict__ in, __hip_bfloat16* __restrict__ out) {
  const int row = blockIdx.x;
  const int t = threadIdx.x;
  const float* src = in + (size_t)row * DD;
  const float v0 = src[t], v1 = src[t + 256], v2 = src[t + 512];
  float s = v0 * v0 + v1 * v1 + v2 * v2;
#pragma unroll
  for (int m = 32; m; m >>= 1) s += __shfl_xor(s, m, 64);
  __shared__ float red[4];
  const int wave = t >> 6, lane = t & 63;
  if (lane == 0) red[wave] = s;
  __syncthreads();
  const float inv = 1.0f / sqrtf(red[0] + red[1] + red[2] + red[3]);
  __hip_bfloat16* dst = out + (size_t)row * DD;
  dst[t]       = __float2bfloat16(v0 * inv);
  dst[t + 256] = __float2bfloat16(v1 * inv);
  dst[t + 512] = __float2bfloat16(v2 * inv);
}

// ---------------- K2: gram row-max GEMM ----------------
// C = F(n) . G(m)^T per (n,m) pair; we only keep rowmax over columns.
// 128x128 tile, BK=64, 4 waves (2x2), mfma 16x16x32 bf16, global_load_lds(16B).
__global__ __launch_bounds__(256) void gram_kernel(
    const __hip_bfloat16* __restrict__ fb, const __hip_bfloat16* __restrict__ gb,
    unsigned* __restrict__ rowmaxU) {
  const int mt = blockIdx.x >> 3, nt = blockIdx.x & 7;     // 8x8 tiles
  const int fn = blockIdx.y >> 3, gm = blockIdx.y & 7;     // 8x8 pairs
  const int brow = mt * 128, bcol = nt * 128;
  const short* A = (const short*)(fb + (size_t)fn * PP * DD);
  const short* B = (const short*)(gb + (size_t)gm * PP * DD);

  __shared__ __align__(16) short Al[128 * 64];
  __shared__ __align__(16) short Bl[128 * 64];

  const int t = threadIdx.x;
  const int lane = t & 63, wave = t >> 6;
  const int wr = wave >> 1, wc = wave & 1;   // 2x2 wave grid, each 64x64 out
  const int lr = lane & 15, lk = lane >> 4;  // fragment row / k-group

  f32x4 acc[4][4];
#pragma unroll
  for (int i = 0; i < 4; ++i)
#pragma unroll
    for (int j = 0; j < 4; ++j) acc[i][j] = (f32x4){0.f, 0.f, 0.f, 0.f};

  for (int kt = 0; kt < DD / 64; ++kt) {
    const int k0 = kt * 64;
    // Stage A tile (128x64 bf16 = 16KB = 1024 x 16B chunks; 4 issues/thread)
#pragma unroll
    for (int i = 0; i < 4; ++i) {
      const int c = i * 256 + t;        // chunk id = i*256 + wave*64 + lane
      const int row = c >> 3;           // 8 chunks per 64-elem row
      const int kc = (c & 7) << 3;
      const short* ga = A + (size_t)(brow + row) * DD + k0 + kc;
      __builtin_amdgcn_global_load_lds(
          (const __attribute__((address_space(1))) void*)ga,
          (__attribute__((address_space(3))) void*)&Al[(i * 256 + wave * 64) * 8],
          16, 0, 0);
    }
#pragma unroll
    for (int i = 0; i < 4; ++i) {
      const int c = i * 256 + t;
      const int row = c >> 3;
      const int kc = (c & 7) << 3;
      const short* gB = B + (size_t)(bcol + row) * DD + k0 + kc;
      __builtin_amdgcn_global_load_lds(
          (const __attribute__((address_space(1))) void*)gB,
          (__attribute__((address_space(3))) void*)&Bl[(i * 256 + wave * 64) * 8],
          16, 0, 0);
    }
    __syncthreads();  // compiler emits vmcnt(0) drain before barrier
#pragma unroll
    for (int ks = 0; ks < 2; ++ks) {
      bf16x8 af[4], bfr[4];
#pragma unroll
      for (int m = 0; m < 4; ++m)
        af[m] = *(const bf16x8*)&Al[(wr * 64 + m * 16 + lr) * 64 + ks * 32 + lk * 8];
#pragma unroll
      for (int n = 0; n < 4; ++n)
        bfr[n] = *(const bf16x8*)&Bl[(wc * 64 + n * 16 + lr) * 64 + ks * 32 + lk * 8];
#pragma unroll
      for (int m = 0; m < 4; ++m)
#pragma unroll
        for (int n = 0; n < 4; ++n)
          acc[m][n] = __builtin_amdgcn_mfma_f32_16x16x32_bf16(af[m], bfr[n],
                                                              acc[m][n], 0, 0, 0);
    }
    __syncthreads();
  }

  // Row-max epilogue. C/D layout: col = lane&15, row = (lane>>4)*4 + reg.
  unsigned* rm = rowmaxU + (size_t)(fn * 8 + gm) * PP;
#pragma unroll
  for (int m = 0; m < 4; ++m) {
#pragma unroll
    for (int r = 0; r < 4; ++r) {
      float v = fmaxf(fmaxf(acc[m][0][r], acc[m][1][r]),
                      fmaxf(acc[m][2][r], acc[m][3][r]));
      v = fmaxf(v, __shfl_xor(v, 1, 64));
      v = fmaxf(v, __shfl_xor(v, 2, 64));
      v = fmaxf(v, __shfl_xor(v, 4, 64));
      v = fmaxf(v, __shfl_xor(v, 8, 64));
      if (lr == 0) {
        const int row = brow + wr * 64 + m * 16 + lk * 4 + r;
        atomicMax(&rm[row], f2u_mono(v));
      }
    }
  }
}

// ---------------- K3: rowmax -> dist -> scores + sp ----------------
// One block per n (8 blocks). dist = 0.5*sqrt(max(0, 2-2*gram)).
__global__ __launch_bounds__(256) void finalize_kernel(
    const unsigned* __restrict__ rowmaxU, float* __restrict__ sp,
    float* __restrict__ scores) {
  const int n = blockIdx.x, t = threadIdx.x;
  const int lane = t & 63, wave = t >> 6;
  __shared__ float red[4];
  __shared__ float maxd[N2];
  float spacc[4] = {0.f, 0.f, 0.f, 0.f};
  for (int m = 0; m < N2; ++m) {
    float lmax = -1e30f;
#pragma unroll
    for (int i = 0; i < 4; ++i) {
      const int p = t + i * 256;
      const float g = u2f_mono(rowmaxU[(size_t)(n * N2 + m) * PP + p]);
      const float d = 0.5f * sqrtf(fmaxf(0.f, 2.f - 2.f * g));
      spacc[i] += d;
      lmax = fmaxf(lmax, d);
    }
#pragma unroll
    for (int msk = 32; msk; msk >>= 1) lmax = fmaxf(lmax, __shfl_xor(lmax, msk, 64));
    if (lane == 0) red[wave] = lmax;
    __syncthreads();
    if (t == 0) maxd[m] = fmaxf(fmaxf(red[0], red[1]), fmaxf(red[2], red[3]));
    __syncthreads();
  }
  if (t == 0) {
    float s = 0.f;
    for (int m = 0; m < N2; ++m) s += maxd[m];
    scores[n] = s * (1.0f / N2);
  }
#pragma unroll
  for (int i = 0; i < 4; ++i)
    sp[(size_t)n * PP + t + i * 256] = spacc[i] * (1.0f / N2);
}

// ---------------- K4: bilinear resize 32x32 -> 512x512 ----------------
__global__ __launch_bounds__(256) void resize_kernel(
    const float* __restrict__ sp, float* __restrict__ out) {
  const int idx = blockIdx.x * 256 + threadIdx.x;
  const int ox = idx & (OW - 1);
  const int oy = (idx >> 9) & (OH - 1);
  const int n = idx >> 18;
  const float sy = (oy + 0.5f) * ((float)PH / OH) - 0.5f;
  const float sx = (ox + 0.5f) * ((float)PW / OW) - 0.5f;
  const float y0f = floorf(sy), x0f = floorf(sx);
  const float wy = sy - y0f, wx = sx - x0f;
  int y0 = (int)y0f, x0 = (int)x0f;
  int y1 = y0 + 1, x1 = x0 + 1;
  y0 = min(max(y0, 0), PH - 1);
  y1 = min(max(y1, 0), PH - 1);
  x0 = min(max(x0, 0), PW - 1);
  x1 = min(max(x1, 0), PW - 1);
  const float* s = sp + (size_t)n * PP;
  const float v00 = s[y0 * PW + x0], v01 = s[y0 * PW + x1];
  const float v10 = s[y1 * PW + x0], v11 = s[y1 * PW + x1];
  const float top = v00 * (1.f - wx) + v01 * wx;
  const float bot = v10 * (1.f - wx) + v11 * wx;
  out[idx] = top * (1.f - wy) + bot * wy;
}

extern "C" void kernel_launch(void* const* d_in, const int* in_sizes, int n_in,
                              void* d_out, int out_size, void* d_ws, size_t ws_size,
                              hipStream_t stream) {
  const float* feats = (const float*)d_in[0];
  const float* nfeats = (const float*)d_in[1];
  float* out = (float*)d_out;

  // Workspace layout (total ~25.5 MB)
  char* ws = (char*)d_ws;
  const size_t FB_BYTES = (size_t)N1 * PP * DD * 2;  // 12,582,912
  __hip_bfloat16* fb = (__hip_bfloat16*)ws;
  __hip_bfloat16* gbuf = (__hip_bfloat16*)(ws + FB_BYTES);
  unsigned* rowmaxU = (unsigned*)(ws + 2 * FB_BYTES);
  float* sp = (float*)(ws + 2 * FB_BYTES + (size_t)N1 * N2 * PP * 4);

  // rowmax sentinel: monotone-mapped 0 == -inf
  hipMemsetAsync(rowmaxU, 0, (size_t)N1 * N2 * PP * 4, stream);

  nrm_kernel<<<N1 * PP, 256, 0, stream>>>(feats, fb);
  nrm_kernel<<<N2 * PP, 256, 0, stream>>>(nfeats, gbuf);

  gram_kernel<<<dim3(64, 64), 256, 0, stream>>>(fb, gbuf, rowmaxU);

  finalize_kernel<<<N1, 256, 0, stream>>>(rowmaxU, sp, out);
  resize_kernel<<<(N1 * OH * OW) / 256, 256, 0, stream>>>(sp, out + 8);
}

// Round 2
// 166.547 us; speedup vs baseline: 1.2211x; 1.2211x over previous
//
#include <hip/hip_runtime.h>
#include <hip/hip_bf16.h>
#include <stdint.h>

// Problem constants (from reference)
#define N1 8
#define N2 8
#define PP 1024
#define DD 768
#define PH 32
#define PW 32
#define OH 512
#define OW 512

#define NKT 24   // 768 / 32 K-tiles

typedef short bf16x8 __attribute__((ext_vector_type(8)));
typedef float f32x4 __attribute__((ext_vector_type(4)));

// Monotone float<->uint mapping so atomicMax on unsigned == max on float.
__device__ __forceinline__ unsigned f2u_mono(float f) {
  unsigned u = __float_as_uint(f);
  return (u & 0x80000000u) ? ~u : (u | 0x80000000u);
}
__device__ __forceinline__ float u2f_mono(unsigned u) {
  return (u & 0x80000000u) ? __uint_as_float(u & 0x7fffffffu)
                           : __uint_as_float(~u);
}

__device__ __forceinline__ void gll16(const short* src, short* dst) {
  __builtin_amdgcn_global_load_lds(
      (const __attribute__((address_space(1))) void*)src,
      (__attribute__((address_space(3))) void*)dst, 16, 0, 0);
}

// ---------------- K1: row L2-normalize f32 -> bf16 ----------------
__global__ __launch_bounds__(256) void nrm_kernel(
    const float* __restrict__ in, __hip_bfloat16* __restrict__ out) {
  const int row = blockIdx.x;
  const int t = threadIdx.x;
  const float* src = in + (size_t)row * DD;
  const float v0 = src[t], v1 = src[t + 256], v2 = src[t + 512];
  float s = v0 * v0 + v1 * v1 + v2 * v2;
#pragma unroll
  for (int m = 32; m; m >>= 1) s += __shfl_xor(s, m, 64);
  __shared__ float red[4];
  const int wave = t >> 6, lane = t & 63;
  if (lane == 0) red[wave] = s;
  __syncthreads();
  const float inv = 1.0f / sqrtf(red[0] + red[1] + red[2] + red[3]);
  __hip_bfloat16* dst = out + (size_t)row * DD;
  dst[t]       = __float2bfloat16(v0 * inv);
  dst[t + 256] = __float2bfloat16(v1 * inv);
  dst[t + 512] = __float2bfloat16(v2 * inv);
}

// ---------------- K2: gram row-max GEMM, 256x256 tile, BK=32, 4-slot pipe ----
// 8 waves (2M x 4N), per-wave C = 128x64. LDS slot = A[256][32]+B[256][32]
// bf16 (32KB); 4 slots = 128 KiB. While computing kt k (slot k&3) we stage
// kt k+3 (slot (k+3)&3) -> read/write slots always disjoint (race-free).
// Counted vmcnt(8) at each kt boundary keeps 2 kt (8 loads) in flight.
// LDS swizzle: byte y in a 16KB buffer holds global data at S(y)=y^(((y>>7)&7)<<4)
// (involution); ds_read uses the same XOR -> 2 lanes/bank (free).
__global__ __launch_bounds__(512, 2) void gram8_kernel(
    const __hip_bfloat16* __restrict__ fb, const __hip_bfloat16* __restrict__ gb,
    unsigned* __restrict__ rowmaxU) {
  __shared__ __align__(16) short lds[4][2][8192];  // [slot][A/B][256*32]

  // XCD swizzle: 1024 wgs -> 128 contiguous per XCD (one fn per XCD).
  const int bid = blockIdx.x;
  const int wg = (bid & 7) * 128 + (bid >> 3);
  const int pair = wg >> 4;  // 0..63
  const int tile = wg & 15;
  const int fn = pair >> 3, gm = pair & 7;
  const int mt = tile >> 2, nt = tile & 3;
  const int brow = mt * 256, bcol = nt * 256;

  const int t = threadIdx.x;
  const int lane = t & 63, wave = t >> 6;
  const int lr = lane & 15, lk = lane >> 4;
  const int wr = wave >> 2, wc = wave & 3;  // 2M x 4N wave grid

  const short* rowA = (const short*)fb + ((size_t)fn * PP + brow) * DD;
  const short* rowB = (const short*)gb + ((size_t)gm * PP + bcol) * DD;

  // Staging source mapping (constant per thread), group g in {0,1}:
  // chunk c holds LDS bytes [c*16, c*16+16); data there = global at S(c*16).
  int srow[2], scol[2];
#pragma unroll
  for (int g = 0; g < 2; ++g) {
    const int c = g * 512 + wave * 64 + lane;
    const int y = c * 16;
    const int x = y ^ (((y >> 7) & 7) << 4);
    srow[g] = x >> 6;         // 64-B rows (32 bf16)
    scol[g] = (x & 63) >> 1;
  }
  const int ldst[2] = {(0 * 512 + wave * 64) * 8, (1 * 512 + wave * 64) * 8};

  // Fragment read offsets (bytes) within a 16KB buffer, + m*1024 / + n*1024.
  const int v = (lr >> 1) << 4;
  const int ya0 = (((wr * 128 + lr) * 64) + lk * 16) ^ v;
  const int yb0 = (((wc * 64 + lr) * 64) + lk * 16) ^ v;

  f32x4 acc[8][4];
#pragma unroll
  for (int i = 0; i < 8; ++i)
#pragma unroll
    for (int j = 0; j < 4; ++j) acc[i][j] = (f32x4){0.f, 0.f, 0.f, 0.f};

  // Prologue: stage kt 0,1,2 into slots 0,1,2 (12 loads/thread).
#pragma unroll
  for (int kk = 0; kk < 3; ++kk) {
    const int k0 = kk * 32;
#pragma unroll
    for (int g = 0; g < 2; ++g)
      gll16(rowA + (size_t)srow[g] * DD + k0 + scol[g], &lds[kk][0][ldst[g]]);
#pragma unroll
    for (int g = 0; g < 2; ++g)
      gll16(rowB + (size_t)srow[g] * DD + k0 + scol[g], &lds[kk][1][ldst[g]]);
  }
  asm volatile("s_waitcnt vmcnt(8)" ::: "memory");  // kt0 resident
  __builtin_amdgcn_s_barrier();

#pragma unroll 1
  for (int k = 0; k < NKT; ++k) {
    const short* As = &lds[k & 3][0][0];
    const short* Bs = &lds[k & 3][1][0];
    const bool st = (k + 3 < NKT);
    const int ss = (k + 3) & 3;
    const int k0s = (k + 3) * 32;
    bf16x8 a[4], b[4];

    // ---- phase 0 (m 0..3) : 8 ds_read_b128 + stage A of kt k+3 ----
#pragma unroll
    for (int m = 0; m < 4; ++m)
      a[m] = *(const bf16x8*)((const char*)As + ya0 + m * 1024);
#pragma unroll
    for (int n = 0; n < 4; ++n)
      b[n] = *(const bf16x8*)((const char*)Bs + yb0 + n * 1024);
    if (st) {
#pragma unroll
      for (int g = 0; g < 2; ++g)
        gll16(rowA + (size_t)srow[g] * DD + k0s + scol[g], &lds[ss][0][ldst[g]]);
    }
    __builtin_amdgcn_s_barrier();
    asm volatile("s_waitcnt lgkmcnt(0)" ::: "memory");
    __builtin_amdgcn_s_setprio(1);
#pragma unroll
    for (int m = 0; m < 4; ++m)
#pragma unroll
      for (int n = 0; n < 4; ++n)
        acc[m][n] = __builtin_amdgcn_mfma_f32_16x16x32_bf16(a[m], b[n],
                                                            acc[m][n], 0, 0, 0);
    __builtin_amdgcn_s_setprio(0);
    __builtin_amdgcn_s_barrier();

    // ---- phase 1 (m 4..7) : 4 ds_read_b128 + stage B of kt k+3 ----
#pragma unroll
    for (int m = 0; m < 4; ++m)
      a[m] = *(const bf16x8*)((const char*)As + ya0 + (m + 4) * 1024);
    if (st) {
#pragma unroll
      for (int g = 0; g < 2; ++g)
        gll16(rowB + (size_t)srow[g] * DD + k0s + scol[g], &lds[ss][1][ldst[g]]);
    }
    __builtin_amdgcn_s_barrier();
    asm volatile("s_waitcnt lgkmcnt(0)" ::: "memory");
    __builtin_amdgcn_s_setprio(1);
#pragma unroll
    for (int m = 0; m < 4; ++m)
#pragma unroll
      for (int n = 0; n < 4; ++n)
        acc[m + 4][n] = __builtin_amdgcn_mfma_f32_16x16x32_bf16(
            a[m], b[n], acc[m + 4][n], 0, 0, 0);
    __builtin_amdgcn_s_setprio(0);
    // kt boundary: ensure kt k+1's slot resident; keep 2 kt (8 loads) in flight.
    if (k < NKT - 3) {
      asm volatile("s_waitcnt vmcnt(8)" ::: "memory");
    } else if (k == NKT - 3) {
      asm volatile("s_waitcnt vmcnt(4)" ::: "memory");
    } else if (k == NKT - 2) {
      asm volatile("s_waitcnt vmcnt(0)" ::: "memory");
    }
    __builtin_amdgcn_s_barrier();
  }

  // Row-max epilogue. C/D layout: col = lane&15 (lr), row = lk*4 + reg.
  unsigned* rm = rowmaxU + (size_t)(fn * 8 + gm) * PP;
#pragma unroll
  for (int m = 0; m < 8; ++m) {
#pragma unroll
    for (int r = 0; r < 4; ++r) {
      float vv = fmaxf(fmaxf(acc[m][0][r], acc[m][1][r]),
                       fmaxf(acc[m][2][r], acc[m][3][r]));
      vv = fmaxf(vv, __shfl_xor(vv, 1, 64));
      vv = fmaxf(vv, __shfl_xor(vv, 2, 64));
      vv = fmaxf(vv, __shfl_xor(vv, 4, 64));
      vv = fmaxf(vv, __shfl_xor(vv, 8, 64));
      if (lr == 0) {
        const int row = brow + wr * 128 + m * 16 + lk * 4 + r;
        atomicMax(&rm[row], f2u_mono(vv));
      }
    }
  }
}

// ---------------- K3: rowmax -> dist -> scores + sp ----------------
__global__ __launch_bounds__(256) void finalize_kernel(
    const unsigned* __restrict__ rowmaxU, float* __restrict__ sp,
    float* __restrict__ scores) {
  const int n = blockIdx.x, t = threadIdx.x;
  const int lane = t & 63, wave = t >> 6;
  __shared__ float red[4];
  __shared__ float maxd[N2];
  float spacc[4] = {0.f, 0.f, 0.f, 0.f};
  for (int m = 0; m < N2; ++m) {
    float lmax = -1e30f;
#pragma unroll
    for (int i = 0; i < 4; ++i) {
      const int p = t + i * 256;
      const float g = u2f_mono(rowmaxU[(size_t)(n * N2 + m) * PP + p]);
      const float d = 0.5f * sqrtf(fmaxf(0.f, 2.f - 2.f * g));
      spacc[i] += d;
      lmax = fmaxf(lmax, d);
    }
#pragma unroll
    for (int msk = 32; msk; msk >>= 1) lmax = fmaxf(lmax, __shfl_xor(lmax, msk, 64));
    if (lane == 0) red[wave] = lmax;
    __syncthreads();
    if (t == 0) maxd[m] = fmaxf(fmaxf(red[0], red[1]), fmaxf(red[2], red[3]));
    __syncthreads();
  }
  if (t == 0) {
    float s = 0.f;
    for (int m = 0; m < N2; ++m) s += maxd[m];
    scores[n] = s * (1.0f / N2);
  }
#pragma unroll
  for (int i = 0; i < 4; ++i)
    sp[(size_t)n * PP + t + i * 256] = spacc[i] * (1.0f / N2);
}

// ---------------- K4: bilinear resize 32x32 -> 512x512 ----------------
__global__ __launch_bounds__(256) void resize_kernel(
    const float* __restrict__ sp, float* __restrict__ out) {
  const int idx = blockIdx.x * 256 + threadIdx.x;
  const int ox = idx & (OW - 1);
  const int oy = (idx >> 9) & (OH - 1);
  const int n = idx >> 18;
  const float sy = (oy + 0.5f) * ((float)PH / OH) - 0.5f;
  const float sx = (ox + 0.5f) * ((float)PW / OW) - 0.5f;
  const float y0f = floorf(sy), x0f = floorf(sx);
  const float wy = sy - y0f, wx = sx - x0f;
  int y0 = (int)y0f, x0 = (int)x0f;
  int y1 = y0 + 1, x1 = x0 + 1;
  y0 = min(max(y0, 0), PH - 1);
  y1 = min(max(y1, 0), PH - 1);
  x0 = min(max(x0, 0), PW - 1);
  x1 = min(max(x1, 0), PW - 1);
  const float* s = sp + (size_t)n * PP;
  const float v00 = s[y0 * PW + x0], v01 = s[y0 * PW + x1];
  const float v10 = s[y1 * PW + x0], v11 = s[y1 * PW + x1];
  const float top = v00 * (1.f - wx) + v01 * wx;
  const float bot = v10 * (1.f - wx) + v11 * wx;
  out[idx] = top * (1.f - wy) + bot * wy;
}

extern "C" void kernel_launch(void* const* d_in, const int* in_sizes, int n_in,
                              void* d_out, int out_size, void* d_ws, size_t ws_size,
                              hipStream_t stream) {
  const float* feats = (const float*)d_in[0];
  const float* nfeats = (const float*)d_in[1];
  float* out = (float*)d_out;

  char* ws = (char*)d_ws;
  const size_t FB_BYTES = (size_t)N1 * PP * DD * 2;  // 12,582,912
  __hip_bfloat16* fb = (__hip_bfloat16*)ws;
  __hip_bfloat16* gbuf = (__hip_bfloat16*)(ws + FB_BYTES);
  unsigned* rowmaxU = (unsigned*)(ws + 2 * FB_BYTES);
  float* sp = (float*)(ws + 2 * FB_BYTES + (size_t)N1 * N2 * PP * 4);

  // rowmax sentinel: monotone-mapped 0 == -inf
  hipMemsetAsync(rowmaxU, 0, (size_t)N1 * N2 * PP * 4, stream);

  nrm_kernel<<<N1 * PP, 256, 0, stream>>>(feats, fb);
  nrm_kernel<<<N2 * PP, 256, 0, stream>>>(nfeats, gbuf);

  gram8_kernel<<<1024, 512, 0, stream>>>(fb, gbuf, rowmaxU);

  finalize_kernel<<<N1, 256, 0, stream>>>(rowmaxU, sp, out);
  resize_kernel<<<(N1 * OH * OW) / 256, 256, 0, stream>>>(sp, out + 8);
}

// Round 3
// 160.986 us; speedup vs baseline: 1.2632x; 1.0345x over previous
//
#include <hip/hip_runtime.h>
#include <hip/hip_bf16.h>
#include <stdint.h>

// Problem constants (from reference)
#define N1 8
#define N2 8
#define PP 1024
#define DD 768
#define PH 32
#define PW 32
#define OH 512
#define OW 512

#define NKT 24   // 768 / 32 K-tiles

typedef short bf16x8 __attribute__((ext_vector_type(8)));
typedef float f32x4 __attribute__((ext_vector_type(4)));

// Monotone float<->uint mapping so atomicMax on unsigned == max on float.
__device__ __forceinline__ unsigned f2u_mono(float f) {
  unsigned u = __float_as_uint(f);
  return (u & 0x80000000u) ? ~u : (u | 0x80000000u);
}
__device__ __forceinline__ float u2f_mono(unsigned u) {
  return (u & 0x80000000u) ? __uint_as_float(u & 0x7fffffffu)
                           : __uint_as_float(~u);
}

__device__ __forceinline__ void gll16(const short* src, short* dst) {
  __builtin_amdgcn_global_load_lds(
      (const __attribute__((address_space(1))) void*)src,
      (__attribute__((address_space(3))) void*)dst, 16, 0, 0);
}

// ---------------- K1: row L2-normalize f32 -> bf16 (both tensors) ----------
__global__ __launch_bounds__(256) void nrm_kernel(
    const float* __restrict__ inA, const float* __restrict__ inB,
    __hip_bfloat16* __restrict__ outA, __hip_bfloat16* __restrict__ outB) {
  int row = blockIdx.x;
  const float* src;
  __hip_bfloat16* dst;
  if (row < N1 * PP) {
    src = inA + (size_t)row * DD;
    dst = outA + (size_t)row * DD;
  } else {
    row -= N1 * PP;
    src = inB + (size_t)row * DD;
    dst = outB + (size_t)row * DD;
  }
  const int t = threadIdx.x;
  const float v0 = src[t], v1 = src[t + 256], v2 = src[t + 512];
  float s = v0 * v0 + v1 * v1 + v2 * v2;
#pragma unroll
  for (int m = 32; m; m >>= 1) s += __shfl_xor(s, m, 64);
  __shared__ float red[4];
  const int wave = t >> 6, lane = t & 63;
  if (lane == 0) red[wave] = s;
  __syncthreads();
  const float inv = 1.0f / sqrtf(red[0] + red[1] + red[2] + red[3]);
  dst[t]       = __float2bfloat16(v0 * inv);
  dst[t + 256] = __float2bfloat16(v1 * inv);
  dst[t + 512] = __float2bfloat16(v2 * inv);
}

// ---------------- K2: gram row-max GEMM, 256x256 tile, BK=32, 4-slot pipe ----
// 8 waves (2M x 4N), per-wave C = 128x64. LDS slot = A[256][32]+B[256][32]
// bf16 (32KB); 4 slots = 128 KiB. While computing kt k (slot k&3) we stage
// kt k+3 (slot (k+3)&3 == (k-1)&3, freed at end of kt k-1) -> disjoint.
//
// WAVE-DRIFT SCHEDULE (R2): ONE barrier + ONE counted vmcnt per kt, no
// intra-kt barriers and no lgkmcnt(0) drains. Safety:
//  - slot k resident: vmcnt at end of kt k-1 drains kt k's 4 loads + barrier.
//  - slot (k+3)&3 free to stage during kt k: all ds_reads of it (kt k-1)
//    were consumed by MFMAs before the end-of-kt-(k-1) barrier (DS ops
//    retire in order; compiler's per-MFMA lgkmcnt waits drain them).
// Waves drift within a kt -> LDS reads of one wave overlap MFMA of another.
//
// LDS swizzle: byte y in a 16KB buffer holds global data at
// S(y)=y^(((y>>7)&7)<<4) (involution); ds_read uses the same XOR ->
// 2 lanes/bank (free). Verified: 0 bank conflicts in R1.
__global__ __launch_bounds__(512, 2) void gram8_kernel(
    const __hip_bfloat16* __restrict__ fb, const __hip_bfloat16* __restrict__ gb,
    unsigned* __restrict__ rowmaxU) {
  __shared__ __align__(16) short lds[4][2][8192];  // [slot][A/B][256*32]

  // XCD swizzle: 1024 wgs -> 128 contiguous per XCD (one fn per XCD).
  const int bid = blockIdx.x;
  const int wg = (bid & 7) * 128 + (bid >> 3);
  const int pair = wg >> 4;  // 0..63
  const int tile = wg & 15;
  const int fn = pair >> 3, gm = pair & 7;
  const int mt = tile >> 2, nt = tile & 3;
  const int brow = mt * 256, bcol = nt * 256;

  const int t = threadIdx.x;
  const int lane = t & 63, wave = t >> 6;
  const int lr = lane & 15, lk = lane >> 4;
  const int wr = wave >> 2, wc = wave & 3;  // 2M x 4N wave grid

  const short* rowA = (const short*)fb + ((size_t)fn * PP + brow) * DD;
  const short* rowB = (const short*)gb + ((size_t)gm * PP + bcol) * DD;

  // Staging source mapping (constant per thread), group g in {0,1}:
  // chunk c holds LDS bytes [c*16, c*16+16); data there = global at S(c*16).
  int srow[2], scol[2];
#pragma unroll
  for (int g = 0; g < 2; ++g) {
    const int c = g * 512 + wave * 64 + lane;
    const int y = c * 16;
    const int x = y ^ (((y >> 7) & 7) << 4);
    srow[g] = x >> 6;         // 64-B rows (32 bf16)
    scol[g] = (x & 63) >> 1;
  }
  const int ldst[2] = {(0 * 512 + wave * 64) * 8, (1 * 512 + wave * 64) * 8};

  // Fragment read offsets (bytes) within a 16KB buffer, + m*1024 / + n*1024.
  const int v = (lr >> 1) << 4;
  const int ya0 = (((wr * 128 + lr) * 64) + lk * 16) ^ v;
  const int yb0 = (((wc * 64 + lr) * 64) + lk * 16) ^ v;

  f32x4 acc[8][4];
#pragma unroll
  for (int i = 0; i < 8; ++i)
#pragma unroll
    for (int j = 0; j < 4; ++j) acc[i][j] = (f32x4){0.f, 0.f, 0.f, 0.f};

  // Prologue: stage kt 0,1,2 into slots 0,1,2 (12 loads/thread).
#pragma unroll
  for (int kk = 0; kk < 3; ++kk) {
    const int k0 = kk * 32;
#pragma unroll
    for (int g = 0; g < 2; ++g)
      gll16(rowA + (size_t)srow[g] * DD + k0 + scol[g], &lds[kk][0][ldst[g]]);
#pragma unroll
    for (int g = 0; g < 2; ++g)
      gll16(rowB + (size_t)srow[g] * DD + k0 + scol[g], &lds[kk][1][ldst[g]]);
  }
  asm volatile("s_waitcnt vmcnt(8)" ::: "memory");  // kt0 resident
  __builtin_amdgcn_s_barrier();
  asm volatile("" ::: "memory");

#pragma unroll 1
  for (int k = 0; k < NKT; ++k) {
    const short* As = &lds[k & 3][0][0];
    const short* Bs = &lds[k & 3][1][0];
    bf16x8 a[8], b[4];

    // ds_reads first (compiler inserts fine-grained lgkmcnt before each
    // dependent MFMA; no explicit drain).
#pragma unroll
    for (int m = 0; m < 8; ++m)
      a[m] = *(const bf16x8*)((const char*)As + ya0 + m * 1024);
#pragma unroll
    for (int n = 0; n < 4; ++n)
      b[n] = *(const bf16x8*)((const char*)Bs + yb0 + n * 1024);

    // Stage kt k+3 (slot freed at the end of kt k-1).
    if (k + 3 < NKT) {
      const int ss = (k + 3) & 3;
      const int k0s = (k + 3) * 32;
#pragma unroll
      for (int g = 0; g < 2; ++g)
        gll16(rowA + (size_t)srow[g] * DD + k0s + scol[g], &lds[ss][0][ldst[g]]);
#pragma unroll
      for (int g = 0; g < 2; ++g)
        gll16(rowB + (size_t)srow[g] * DD + k0s + scol[g], &lds[ss][1][ldst[g]]);
    }

    __builtin_amdgcn_s_setprio(1);
#pragma unroll
    for (int m = 0; m < 8; ++m)
#pragma unroll
      for (int n = 0; n < 4; ++n)
        acc[m][n] = __builtin_amdgcn_mfma_f32_16x16x32_bf16(a[m], b[n],
                                                            acc[m][n], 0, 0, 0);
    __builtin_amdgcn_s_setprio(0);

    // kt boundary: slot k+1 must be resident; keep 2 kt (8 loads) in flight.
    if (k < NKT - 3) {
      asm volatile("s_waitcnt vmcnt(8)" ::: "memory");
    } else if (k == NKT - 3) {
      asm volatile("s_waitcnt vmcnt(4)" ::: "memory");
    } else if (k == NKT - 2) {
      asm volatile("s_waitcnt vmcnt(0)" ::: "memory");
    }
    __builtin_amdgcn_s_barrier();
    asm volatile("" ::: "memory");
  }

  // Row-max epilogue. C/D layout: col = lane&15 (lr), row = lk*4 + reg.
  unsigned* rm = rowmaxU + (size_t)(fn * 8 + gm) * PP;
#pragma unroll
  for (int m = 0; m < 8; ++m) {
#pragma unroll
    for (int r = 0; r < 4; ++r) {
      float vv = fmaxf(fmaxf(acc[m][0][r], acc[m][1][r]),
                       fmaxf(acc[m][2][r], acc[m][3][r]));
      vv = fmaxf(vv, __shfl_xor(vv, 1, 64));
      vv = fmaxf(vv, __shfl_xor(vv, 2, 64));
      vv = fmaxf(vv, __shfl_xor(vv, 4, 64));
      vv = fmaxf(vv, __shfl_xor(vv, 8, 64));
      if (lr == 0) {
        const int row = brow + wr * 128 + m * 16 + lk * 4 + r;
        atomicMax(&rm[row], f2u_mono(vv));
      }
    }
  }
}

// ---------------- K3: rowmax -> dist -> scores + sp ----------------
__global__ __launch_bounds__(256) void finalize_kernel(
    const unsigned* __restrict__ rowmaxU, float* __restrict__ sp,
    float* __restrict__ scores) {
  const int n = blockIdx.x, t = threadIdx.x;
  const int lane = t & 63, wave = t >> 6;
  __shared__ float red[4];
  __shared__ float maxd[N2];
  float spacc[4] = {0.f, 0.f, 0.f, 0.f};
  for (int m = 0; m < N2; ++m) {
    float lmax = -1e30f;
#pragma unroll
    for (int i = 0; i < 4; ++i) {
      const int p = t + i * 256;
      const float g = u2f_mono(rowmaxU[(size_t)(n * N2 + m) * PP + p]);
      const float d = 0.5f * sqrtf(fmaxf(0.f, 2.f - 2.f * g));
      spacc[i] += d;
      lmax = fmaxf(lmax, d);
    }
#pragma unroll
    for (int msk = 32; msk; msk >>= 1) lmax = fmaxf(lmax, __shfl_xor(lmax, msk, 64));
    if (lane == 0) red[wave] = lmax;
    __syncthreads();
    if (t == 0) maxd[m] = fmaxf(fmaxf(red[0], red[1]), fmaxf(red[2], red[3]));
    __syncthreads();
  }
  if (t == 0) {
    float s = 0.f;
    for (int m = 0; m < N2; ++m) s += maxd[m];
    scores[n] = s * (1.0f / N2);
  }
#pragma unroll
  for (int i = 0; i < 4; ++i)
    sp[(size_t)n * PP + t + i * 256] = spacc[i] * (1.0f / N2);
}

// ---------------- K4: bilinear resize 32x32 -> 512x512 ----------------
__global__ __launch_bounds__(256) void resize_kernel(
    const float* __restrict__ sp, float* __restrict__ out) {
  const int idx = blockIdx.x * 256 + threadIdx.x;
  const int ox = idx & (OW - 1);
  const int oy = (idx >> 9) & (OH - 1);
  const int n = idx >> 18;
  const float sy = (oy + 0.5f) * ((float)PH / OH) - 0.5f;
  const float sx = (ox + 0.5f) * ((float)PW / OW) - 0.5f;
  const float y0f = floorf(sy), x0f = floorf(sx);
  const float wy = sy - y0f, wx = sx - x0f;
  int y0 = (int)y0f, x0 = (int)x0f;
  int y1 = y0 + 1, x1 = x0 + 1;
  y0 = min(max(y0, 0), PH - 1);
  y1 = min(max(y1, 0), PH - 1);
  x0 = min(max(x0, 0), PW - 1);
  x1 = min(max(x1, 0), PW - 1);
  const float* s = sp + (size_t)n * PP;
  const float v00 = s[y0 * PW + x0], v01 = s[y0 * PW + x1];
  const float v10 = s[y1 * PW + x0], v11 = s[y1 * PW + x1];
  const float top = v00 * (1.f - wx) + v01 * wx;
  const float bot = v10 * (1.f - wx) + v11 * wx;
  out[idx] = top * (1.f - wy) + bot * wy;
}

extern "C" void kernel_launch(void* const* d_in, const int* in_sizes, int n_in,
                              void* d_out, int out_size, void* d_ws, size_t ws_size,
                              hipStream_t stream) {
  const float* feats = (const float*)d_in[0];
  const float* nfeats = (const float*)d_in[1];
  float* out = (float*)d_out;

  char* ws = (char*)d_ws;
  const size_t FB_BYTES = (size_t)N1 * PP * DD * 2;  // 12,582,912
  __hip_bfloat16* fb = (__hip_bfloat16*)ws;
  __hip_bfloat16* gbuf = (__hip_bfloat16*)(ws + FB_BYTES);
  unsigned* rowmaxU = (unsigned*)(ws + 2 * FB_BYTES);
  float* sp = (float*)(ws + 2 * FB_BYTES + (size_t)N1 * N2 * PP * 4);

  // rowmax sentinel: monotone-mapped 0 == -inf
  hipMemsetAsync(rowmaxU, 0, (size_t)N1 * N2 * PP * 4, stream);

  nrm_kernel<<<(N1 + N2) * PP, 256, 0, stream>>>(feats, nfeats, fb, gbuf);

  gram8_kernel<<<1024, 512, 0, stream>>>(fb, gbuf, rowmaxU);

  finalize_kernel<<<N1, 256, 0, stream>>>(rowmaxU, sp, out);
  resize_kernel<<<(N1 * OH * OW) / 256, 256, 0, stream>>>(sp, out + 8);
}